// Round 4
// baseline (649.621 us; speedup 1.0000x reference)
//
#include <hip/hip_runtime.h>

#define DD 128
#define HH 512
#define WW 512
#define NVOX (DD*HH*WW)          // 33554432
#define THRESHV 0.997f
#define KPEAKS 131072
#define PEAK_CAP (1u<<18)        // 262144 peak slots (expect ~63K)
#define NBINS 65536
#define TBLK 256u                // k_tail blocks (== bins/256, == blocksum count)

// peaks all lie in (0.997, 1.0): float bits have constant upper 16 bits
// 0x3F7F -> low 16 bits monotone in value. bin=(~bits)&0xFFFF so ascending
// bin == descending value. Exact-value ties are COMMON -> tie-fix required.

// ---------------- K0: init scratch (ws is poisoned 0xAA before every call).
// counters[8..10] double as k_tail's spin-barrier slots (must be zero).
__global__ void k_init(unsigned* counters, unsigned* hist) {
    unsigned t = blockIdx.x * 1024u + threadIdx.x;
    if (t < 64) counters[t] = 0u;
    if (t < NBINS) hist[t] = 0u;
}

// ---------------- K1: FUSED stream + verify + centroid. 512 thr x 4096 blk.
// R12: reverted VERBATIM to the R0 version (best measured: 84.4us). The R9
// pipelined-DMA (94us, L2-cold verify), R10 register-staged (91us, compiler
// kept VGPR=28 and serialized loads), and R11 split (92us verify alone,
// FETCH 300MB) all lost to this layout: verify runs right after the block's
// slab streamed through L2 -> neighborhood reads are cache-warm.
__global__ __launch_bounds__(512, 8)
void k_find(const float4* __restrict__ vol4, const float* __restrict__ vol,
            unsigned* counters, unsigned* hist,
            unsigned long long* keys, float4* psums) {
    __shared__ float4 tile[2048];             // 32KB: the block's voxel tile
    __shared__ unsigned lcnt, pcnt, lbase;
    __shared__ unsigned cidx[384];            // candidate voxel indices (E~25)
    __shared__ unsigned long long lbuf[192];  // surviving peak keys (E~16)
    __shared__ float4 sbuf[192];              // surviving peak centroid sums
    if (threadIdx.x == 0) { lcnt = 0; pcnt = 0; }
    __syncthreads();

    unsigned t = threadIdx.x;
    unsigned lane = t & 63u;
    unsigned w = t >> 6;                      // wave id 0..7 (wave-uniform)
    unsigned blockBase4 = blockIdx.x * 2048u; // float4 units

    // ---- Phase A: async DMA global -> LDS (4 x 16B per thread, all in flight)
#pragma unroll
    for (unsigned i = 0; i < 4; i++) {
        unsigned f = i * 512u + w * 64u;      // wave-uniform float4 slot base
        const float4* gp = vol4 + blockBase4 + f + lane;
        __builtin_amdgcn_global_load_lds(
            (const __attribute__((address_space(1))) unsigned int*)gp,
            (__attribute__((address_space(3))) unsigned int*)(tile + f),
            16, 0, 0);
    }
    __builtin_amdgcn_s_waitcnt(0);
    __syncthreads();

    // ---- threshold scan from LDS
    unsigned m = 0u;
    float4 v[4];
#pragma unroll
    for (unsigned i = 0; i < 4; i++) v[i] = tile[i * 512u + t];
#pragma unroll
    for (unsigned i = 0; i < 4; i++) {
        m |= (v[i].x > THRESHV ? 1u : 0u) << (4 * i);
        m |= (v[i].y > THRESHV ? 1u : 0u) << (4 * i + 1);
        m |= (v[i].z > THRESHV ? 1u : 0u) << (4 * i + 2);
        m |= (v[i].w > THRESHV ? 1u : 0u) << (4 * i + 3);
    }
    while (m) {
        int b = __ffs(m) - 1;
        m &= m - 1u;
        unsigned f4 = blockBase4 + (unsigned)(b >> 2) * 512u + t;
        cidx[atomicAdd(&lcnt, 1u) & 383u] = f4 * 4u + (unsigned)(b & 3);
    }
    __syncthreads();

    // ---- Phase B: verify, 2 candidates per wave iteration (8 waves)
    unsigned n = lcnt > 384u ? 384u : lcnt;
    int dz = (int)lane / 7, dy = (int)lane - dz * 7;   // meaningful for lane<49
    for (unsigned base = w * 2u; base < n; base += 16u) {
        bool has2 = (base + 1u < n);
        unsigned idxA = cidx[base];
        unsigned idxB = has2 ? cidx[base + 1u] : idxA;
        int zA = idxA >> 18, yA = (idxA >> 9) & 511, xA = idxA & 511;
        int zB = idxB >> 18, yB = (idxB >> 9) & 511, xB = idxB & 511;
        int nzA = zA + dz - 3, nyA = yA + dy - 3;
        int nzB = zB + dz - 3, nyB = yB + dy - 3;
        bool rowokA = (lane < 49) && ((unsigned)nzA < DD) && ((unsigned)nyA < HH);
        bool rowokB = (lane < 49) && ((unsigned)nzB < DD) && ((unsigned)nyB < HH);
        size_t rbA = rowokA ? (((size_t)(unsigned)nzA << 18) | ((size_t)(unsigned)nyA << 9))
                            : (((size_t)zA << 18) | ((size_t)yA << 9));
        size_t rbB = rowokB ? (((size_t)(unsigned)nzB << 18) | ((size_t)(unsigned)nyB << 9))
                            : (((size_t)zB << 18) | ((size_t)yB << 9));
        float rvA[7], rvB[7];
        bool intAB = (xA >= 3) && (xA <= WW - 4) && (xB >= 3) && (xB <= WW - 4);
        if (intAB) {
            float4 fA0 = *(const float4*)(vol + rbA + (unsigned)(xA - 3));
            float4 fA1 = *(const float4*)(vol + rbA + (unsigned)(xA + 1));
            float4 fB0 = *(const float4*)(vol + rbB + (unsigned)(xB - 3));
            float4 fB1 = *(const float4*)(vol + rbB + (unsigned)(xB + 1));
            rvA[0] = fA0.x; rvA[1] = fA0.y; rvA[2] = fA0.z; rvA[3] = fA0.w;
            rvA[4] = fA1.x; rvA[5] = fA1.y; rvA[6] = fA1.z;
            rvB[0] = fB0.x; rvB[1] = fB0.y; rvB[2] = fB0.z; rvB[3] = fB0.w;
            rvB[4] = fB1.x; rvB[5] = fB1.y; rvB[6] = fB1.z;
        } else {
            // rare x-edge path (wave-uniform): clamped scalar loads
#pragma unroll
            for (int d = 0; d < 7; d++) {
                int nxA = xA + d - 3;
                bool okA = (unsigned)nxA < WW;
                float va = vol[rbA + (unsigned)(okA ? nxA : xA)];
                rvA[d] = okA ? va : 0.f;
                int nxB = xB + d - 3;
                bool okB = (unsigned)nxB < WW;
                float vb = vol[rbB + (unsigned)(okB ? nxB : xB)];
                rvB[d] = okB ? vb : 0.f;
            }
        }
        if (!rowokA) {
#pragma unroll
            for (int d = 0; d < 7; d++) rvA[d] = 0.f;
        }
        if (!rowokB) {
#pragma unroll
            for (int d = 0; d < 7; d++) rvB[d] = 0.f;
        }
        float centerA = __shfl(rvA[3], 24);
        float centerB = __shfl(rvB[3], 24);

        // ---- candidate A
        {
            bool kill = false;
            float s0r = 0.f, sxr = 0.f;
#pragma unroll
            for (int d = 0; d < 7; d++) {
                kill |= rvA[d] > centerA;
                s0r += rvA[d];
                sxr += rvA[d] * (float)(d - 3);
            }
            if (!__any(kill)) {
                float s0 = s0r, sx = sxr;
                float sy = s0r * (float)(dy - 3);
                float sz = s0r * (float)(dz - 3);
                for (int off = 32; off; off >>= 1) {
                    s0 += __shfl_down(s0, off);
                    sx += __shfl_down(sx, off);
                    sy += __shfl_down(sy, off);
                    sz += __shfl_down(sz, off);
                }
                if (lane == 0) {
                    unsigned bits = __float_as_uint(centerA);
                    atomicAdd(&hist[(~bits) & 0xFFFFu], 1u);
                    unsigned li = atomicAdd(&pcnt, 1u);
                    if (li < 192u) {
                        lbuf[li] = ((unsigned long long)bits << 32) | idxA;
                        sbuf[li] = make_float4(s0, sx, sy, sz);
                    }
                }
            }
        }
        // ---- candidate B
        if (has2) {
            bool kill = false;
            float s0r = 0.f, sxr = 0.f;
#pragma unroll
            for (int d = 0; d < 7; d++) {
                kill |= rvB[d] > centerB;
                s0r += rvB[d];
                sxr += rvB[d] * (float)(d - 3);
            }
            if (!__any(kill)) {
                float s0 = s0r, sx = sxr;
                float sy = s0r * (float)(dy - 3);
                float sz = s0r * (float)(dz - 3);
                for (int off = 32; off; off >>= 1) {
                    s0 += __shfl_down(s0, off);
                    sx += __shfl_down(sx, off);
                    sy += __shfl_down(sy, off);
                    sz += __shfl_down(sz, off);
                }
                if (lane == 0) {
                    unsigned bits = __float_as_uint(centerB);
                    atomicAdd(&hist[(~bits) & 0xFFFFu], 1u);
                    unsigned li = atomicAdd(&pcnt, 1u);
                    if (li < 192u) {
                        lbuf[li] = ((unsigned long long)bits << 32) | idxB;
                        sbuf[li] = make_float4(s0, sx, sy, sz);
                    }
                }
            }
        }
    }
    __syncthreads();
    if (threadIdx.x == 0) lbase = atomicAdd(&counters[1], pcnt);
    __syncthreads();
    unsigned np = pcnt > 192u ? 192u : pcnt;
    for (unsigned i = threadIdx.x; i < np; i += 512u) {
        unsigned p = lbase + i;
        if (p < PEAK_CAP) { keys[p] = lbuf[i]; psums[p] = sbuf[i]; }
    }
}

// ---------------- K2 (R12): scan + scatter + finish FUSED into one kernel.
// 256 blocks x 1024 threads -- guaranteed co-resident (16 waves/block, >=1
// block/CU capacity over 256 CUs), so a device-scope spin barrier is safe.
// Replaces: single-block k_scan (1 CU crawling over cross-XCD-dirty hist),
// k_scatter + k_finish launches and their cold inter-kernel gaps.
__device__ __forceinline__ void gbar(unsigned* ctr) {
    __threadfence();                      // release: my writes -> device scope
    __syncthreads();
    if (threadIdx.x == 0) {
        atomicAdd(ctr, 1u);               // device-scope arrive
        while (atomicAdd(ctr, 0u) < TBLK) {}
    }
    __syncthreads();
    __threadfence();                      // acquire: see other blocks' writes
}

__global__ __launch_bounds__(1024, 4)
void k_tail(const unsigned* __restrict__ hist, unsigned* counters,
            unsigned* cursor, unsigned* blocksum,
            const unsigned long long* __restrict__ keys,
            unsigned long long* sorted, unsigned* sslot,
            const float4* __restrict__ psums,
            float4* __restrict__ out, float* __restrict__ valid) {
    __shared__ unsigned sc[256];          // this block's 256-bin inclusive scan
    __shared__ unsigned bs[256];          // the 256 blocksums, scanned
    unsigned t = threadIdx.x;
    unsigned b = blockIdx.x;

    // ---- phase 1: per-block scan of its 256-bin chunk; emit block total.
    unsigned h = 0u;
    if (t < 256u) { h = hist[b * 256u + t]; sc[t] = h; }
    __syncthreads();
    for (unsigned off = 1u; off < 256u; off <<= 1) {
        unsigned v = (t < 256u && t >= off) ? sc[t - off] : 0u;
        __syncthreads();
        if (t < 256u) sc[t] += v;
        __syncthreads();
    }
    if (t == 255u) blocksum[b] = sc[255];
    gbar(&counters[8]);

    // ---- phase 2: every block scans the 256 blocksums; write global cursor.
    if (t < 256u) bs[t] = blocksum[t];
    __syncthreads();
    for (unsigned off = 1u; off < 256u; off <<= 1) {
        unsigned v = (t < 256u && t >= off) ? bs[t - off] : 0u;
        __syncthreads();
        if (t < 256u) bs[t] += v;
        __syncthreads();
    }
    unsigned base_b = (b > 0u) ? bs[b - 1u] : 0u;
    if (t < 256u) cursor[b * 256u + t] = base_b + sc[t] - h;  // excl. prefix
    gbar(&counters[9]);

    // ---- phase 3: scatter (k_scatter body) + zero-fill invalid rows.
    unsigned np = counters[1]; if (np > PEAK_CAP) np = PEAK_CAP;
    unsigned g = b * 1024u + t;           // 0 .. PEAK_CAP-1
    if (g < np) {
        unsigned long long key = keys[g];
        unsigned bits = (unsigned)(key >> 32);
        unsigned pos = atomicAdd(&cursor[(~bits) & 0xFFFFu], 1u);
        if (pos < PEAK_CAP) { sorted[pos] = key; sslot[pos] = g; }
    } else if (g < KPEAKS) {
        out[g] = make_float4(0.f, 0.f, 0.f, 0.f);
        valid[g] = 0.f;
    }
    gbar(&counters[10]);

    // ---- phase 4: tiefix + output (k_finish body).
    if (g >= np) return;
    unsigned long long key = sorted[g];
    unsigned bits = (unsigned)(key >> 32);
    unsigned s = g;
    while (s > 0 && (unsigned)(sorted[s - 1] >> 32) == bits) s--;
    unsigned myidx = (unsigned)key;
    unsigned rank = 0, e = s;
    while (e < np) {
        unsigned long long k2 = sorted[e];
        if ((unsigned)(k2 >> 32) != bits) break;
        if ((unsigned)k2 < myidx) rank++;
        e++;
    }
    unsigned row = s + rank;
    if (row >= KPEAKS) return;
    unsigned idx = myidx;
    int z = idx >> 18, y = (idx >> 9) & 511, x = idx & 511;
    float4 ps = psums[sslot[g]];
    float val = __uint_as_float(bits);
    float xloc = ps.y / ps.x, yloc = ps.z / ps.x, zloc = ps.w / ps.x;
    float xr = ((float)x + xloc - (float)(WW - 1) * 0.5f) * 0.1f;
    float yr = ((float)y + yloc - (float)(HH - 1) * 0.5f) * 0.1f;
    float zr = ((float)z + zloc + 0.5f) * 0.02f - 2.0f;
    out[row] = make_float4(xr, yr, zr, val);
    valid[row] = 1.f;
}

extern "C" void kernel_launch(void* const* d_in, const int* in_sizes, int n_in,
                              void* d_out, int out_size, void* d_ws, size_t ws_size,
                              hipStream_t stream) {
    const float* vol = (const float*)d_in[0];
    // d_in[1] = max_peaks scalar (device); fixed at 131072 for this problem.

    char* w = (char*)d_ws;
    unsigned* counters = (unsigned*)w;                                   // 1 KB
    unsigned* hist     = (unsigned*)(w + 1024);                          // 256 KB
    unsigned* cursor   = (unsigned*)(w + 1024 + NBINS * 4);              // 256 KB
    char* w2 = w + 1024 + 2 * NBINS * 4;
    unsigned long long* keys   = (unsigned long long*)w2;                // 2 MB
    unsigned long long* sorted = keys + PEAK_CAP;                        // 2 MB
    unsigned* sslot = (unsigned*)(sorted + PEAK_CAP);                    // 1 MB
    float4*   psums = (float4*)(sslot + PEAK_CAP);                       // 4 MB
    // total ~9.5 MB of ws

    // blocksum scratch for k_tail phases 1-2: reuse sslot's first 1KB (sslot
    // is first written in phase 3, after blocksum is dead).
    unsigned* blocksum = sslot;

    float* out_rows = (float*)d_out;                 // (131072, 4)
    float* valid = out_rows + (size_t)KPEAKS * 4;    // (131072,)

    k_init<<<NBINS / 1024, 1024, 0, stream>>>(counters, hist);
    k_find<<<NVOX / 8192, 512, 0, stream>>>((const float4*)vol, vol, counters, hist, keys, psums);
    k_tail<<<TBLK, 1024, 0, stream>>>(hist, counters, cursor, blocksum, keys,
                                      sorted, sslot, psums,
                                      (float4*)out_rows, valid);
}

// Round 6
// 242.374 us; speedup vs baseline: 2.6802x; 2.6802x over previous
//
#include <hip/hip_runtime.h>

#define DD 128
#define HH 512
#define WW 512
#define NVOX (DD*HH*WW)          // 33554432
#define THRESHV 0.997f
#define KPEAKS 131072
#define PEAK_CAP (1u<<18)        // 262144 peak slots (expect ~63K)
#define NBINS 65536

// peaks all lie in (0.997, 1.0): float bits have constant upper 16 bits
// 0x3F7F -> low 16 bits monotone in value. bin=(~bits)&0xFFFF so ascending
// bin == descending value. Exact-value ties are COMMON -> tie-fix required.

// ---------------- K0: init scratch (ws is poisoned 0xAA before every call).
__global__ void k_init(unsigned* counters, unsigned* hist) {
    unsigned t = blockIdx.x * 1024u + threadIdx.x;
    if (t < 64) counters[t] = 0u;
    if (t < NBINS) hist[t] = 0u;
}

// ---------------- K1: FUSED stream + verify + centroid. 512 thr x 4096 blk.
// R14: R0-VERBATIM (best measured 84.4us, passed 3x). Failed alternatives,
// for the record: R9 pipelined-DMA w/ end-of-block verify (94us, L2-cold,
// FETCH +63MB); R10 register-staged (VGPR stuck at 28, loads serialized);
// R11 split scan/verify kernels (verify FETCH 300MB, cross-XCD cold);
// R13 per-tile-verify pipeline + spin-barrier tail (core dump). The warmth
// of verify running right after the block's 32KB slab streams through L2
// is worth more than every pipelining scheme tried so far.
__global__ __launch_bounds__(512, 8)
void k_find(const float4* __restrict__ vol4, const float* __restrict__ vol,
            unsigned* counters, unsigned* hist,
            unsigned long long* keys, float4* psums) {
    __shared__ float4 tile[2048];             // 32KB: the block's voxel tile
    __shared__ unsigned lcnt, pcnt, lbase;
    __shared__ unsigned cidx[384];            // candidate voxel indices (E~25)
    __shared__ unsigned long long lbuf[192];  // surviving peak keys (E~16)
    __shared__ float4 sbuf[192];              // surviving peak centroid sums
    if (threadIdx.x == 0) { lcnt = 0; pcnt = 0; }
    __syncthreads();

    unsigned t = threadIdx.x;
    unsigned lane = t & 63u;
    unsigned w = t >> 6;                      // wave id 0..7 (wave-uniform)
    unsigned blockBase4 = blockIdx.x * 2048u; // float4 units

    // ---- Phase A: async DMA global -> LDS (4 x 16B per thread, all in flight)
#pragma unroll
    for (unsigned i = 0; i < 4; i++) {
        unsigned f = i * 512u + w * 64u;      // wave-uniform float4 slot base
        const float4* gp = vol4 + blockBase4 + f + lane;
        __builtin_amdgcn_global_load_lds(
            (const __attribute__((address_space(1))) unsigned int*)gp,
            (__attribute__((address_space(3))) unsigned int*)(tile + f),
            16, 0, 0);
    }
    __builtin_amdgcn_s_waitcnt(0);
    __syncthreads();

    // ---- threshold scan from LDS
    unsigned m = 0u;
    float4 v[4];
#pragma unroll
    for (unsigned i = 0; i < 4; i++) v[i] = tile[i * 512u + t];
#pragma unroll
    for (unsigned i = 0; i < 4; i++) {
        m |= (v[i].x > THRESHV ? 1u : 0u) << (4 * i);
        m |= (v[i].y > THRESHV ? 1u : 0u) << (4 * i + 1);
        m |= (v[i].z > THRESHV ? 1u : 0u) << (4 * i + 2);
        m |= (v[i].w > THRESHV ? 1u : 0u) << (4 * i + 3);
    }
    while (m) {
        int b = __ffs(m) - 1;
        m &= m - 1u;
        unsigned f4 = blockBase4 + (unsigned)(b >> 2) * 512u + t;
        cidx[atomicAdd(&lcnt, 1u) & 383u] = f4 * 4u + (unsigned)(b & 3);
    }
    __syncthreads();

    // ---- Phase B: verify, 2 candidates per wave iteration (8 waves)
    unsigned n = lcnt > 384u ? 384u : lcnt;
    int dz = (int)lane / 7, dy = (int)lane - dz * 7;   // meaningful for lane<49
    for (unsigned base = w * 2u; base < n; base += 16u) {
        bool has2 = (base + 1u < n);
        unsigned idxA = cidx[base];
        unsigned idxB = has2 ? cidx[base + 1u] : idxA;
        int zA = idxA >> 18, yA = (idxA >> 9) & 511, xA = idxA & 511;
        int zB = idxB >> 18, yB = (idxB >> 9) & 511, xB = idxB & 511;
        int nzA = zA + dz - 3, nyA = yA + dy - 3;
        int nzB = zB + dz - 3, nyB = yB + dy - 3;
        bool rowokA = (lane < 49) && ((unsigned)nzA < DD) && ((unsigned)nyA < HH);
        bool rowokB = (lane < 49) && ((unsigned)nzB < DD) && ((unsigned)nyB < HH);
        size_t rbA = rowokA ? (((size_t)(unsigned)nzA << 18) | ((size_t)(unsigned)nyA << 9))
                            : (((size_t)zA << 18) | ((size_t)yA << 9));
        size_t rbB = rowokB ? (((size_t)(unsigned)nzB << 18) | ((size_t)(unsigned)nyB << 9))
                            : (((size_t)zB << 18) | ((size_t)yB << 9));
        float rvA[7], rvB[7];
        bool intAB = (xA >= 3) && (xA <= WW - 4) && (xB >= 3) && (xB <= WW - 4);
        if (intAB) {
            float4 fA0 = *(const float4*)(vol + rbA + (unsigned)(xA - 3));
            float4 fA1 = *(const float4*)(vol + rbA + (unsigned)(xA + 1));
            float4 fB0 = *(const float4*)(vol + rbB + (unsigned)(xB - 3));
            float4 fB1 = *(const float4*)(vol + rbB + (unsigned)(xB + 1));
            rvA[0] = fA0.x; rvA[1] = fA0.y; rvA[2] = fA0.z; rvA[3] = fA0.w;
            rvA[4] = fA1.x; rvA[5] = fA1.y; rvA[6] = fA1.z;
            rvB[0] = fB0.x; rvB[1] = fB0.y; rvB[2] = fB0.z; rvB[3] = fB0.w;
            rvB[4] = fB1.x; rvB[5] = fB1.y; rvB[6] = fB1.z;
        } else {
            // rare x-edge path (wave-uniform): clamped scalar loads
#pragma unroll
            for (int d = 0; d < 7; d++) {
                int nxA = xA + d - 3;
                bool okA = (unsigned)nxA < WW;
                float va = vol[rbA + (unsigned)(okA ? nxA : xA)];
                rvA[d] = okA ? va : 0.f;
                int nxB = xB + d - 3;
                bool okB = (unsigned)nxB < WW;
                float vb = vol[rbB + (unsigned)(okB ? nxB : xB)];
                rvB[d] = okB ? vb : 0.f;
            }
        }
        if (!rowokA) {
#pragma unroll
            for (int d = 0; d < 7; d++) rvA[d] = 0.f;
        }
        if (!rowokB) {
#pragma unroll
            for (int d = 0; d < 7; d++) rvB[d] = 0.f;
        }
        float centerA = __shfl(rvA[3], 24);
        float centerB = __shfl(rvB[3], 24);

        // ---- candidate A
        {
            bool kill = false;
            float s0r = 0.f, sxr = 0.f;
#pragma unroll
            for (int d = 0; d < 7; d++) {
                kill |= rvA[d] > centerA;
                s0r += rvA[d];
                sxr += rvA[d] * (float)(d - 3);
            }
            if (!__any(kill)) {
                float s0 = s0r, sx = sxr;
                float sy = s0r * (float)(dy - 3);
                float sz = s0r * (float)(dz - 3);
                for (int off = 32; off; off >>= 1) {
                    s0 += __shfl_down(s0, off);
                    sx += __shfl_down(sx, off);
                    sy += __shfl_down(sy, off);
                    sz += __shfl_down(sz, off);
                }
                if (lane == 0) {
                    unsigned bits = __float_as_uint(centerA);
                    atomicAdd(&hist[(~bits) & 0xFFFFu], 1u);
                    unsigned li = atomicAdd(&pcnt, 1u);
                    if (li < 192u) {
                        lbuf[li] = ((unsigned long long)bits << 32) | idxA;
                        sbuf[li] = make_float4(s0, sx, sy, sz);
                    }
                }
            }
        }
        // ---- candidate B
        if (has2) {
            bool kill = false;
            float s0r = 0.f, sxr = 0.f;
#pragma unroll
            for (int d = 0; d < 7; d++) {
                kill |= rvB[d] > centerB;
                s0r += rvB[d];
                sxr += rvB[d] * (float)(d - 3);
            }
            if (!__any(kill)) {
                float s0 = s0r, sx = sxr;
                float sy = s0r * (float)(dy - 3);
                float sz = s0r * (float)(dz - 3);
                for (int off = 32; off; off >>= 1) {
                    s0 += __shfl_down(s0, off);
                    sx += __shfl_down(sx, off);
                    sy += __shfl_down(sy, off);
                    sz += __shfl_down(sz, off);
                }
                if (lane == 0) {
                    unsigned bits = __float_as_uint(centerB);
                    atomicAdd(&hist[(~bits) & 0xFFFFu], 1u);
                    unsigned li = atomicAdd(&pcnt, 1u);
                    if (li < 192u) {
                        lbuf[li] = ((unsigned long long)bits << 32) | idxB;
                        sbuf[li] = make_float4(s0, sx, sy, sz);
                    }
                }
            }
        }
    }
    __syncthreads();
    if (threadIdx.x == 0) lbase = atomicAdd(&counters[1], pcnt);
    __syncthreads();
    unsigned np = pcnt > 192u ? 192u : pcnt;
    for (unsigned i = threadIdx.x; i < np; i += 512u) {
        unsigned p = lbase + i;
        if (p < PEAK_CAP) { keys[p] = lbuf[i]; psums[p] = sbuf[i]; }
    }
}

// ---------------- K2a (R14): parallel scan, stage 1. 256 blocks x 256 thr.
// Replaces the single-block 65536-bin Hillis-Steele (1 CU crawling over a
// cross-XCD-dirty histogram, est ~20-25us). Each block scans its 256-bin
// chunk in LDS, writes the block-local EXCLUSIVE prefix to cursor and its
// total to blocksum. Kernel boundary = the global barrier (no spin, no risk).
__global__ void k_scan_a(const unsigned* __restrict__ hist,
                         unsigned* __restrict__ cursor,
                         unsigned* __restrict__ blocksum) {
    __shared__ unsigned sc[256];
    unsigned t = threadIdx.x, b = blockIdx.x;
    unsigned h = hist[b * 256u + t];
    sc[t] = h;
    __syncthreads();
    for (unsigned off = 1u; off < 256u; off <<= 1) {
        unsigned v = (t >= off) ? sc[t - off] : 0u;
        __syncthreads();
        sc[t] += v;
        __syncthreads();
    }
    cursor[b * 256u + t] = sc[t] - h;         // block-local exclusive
    if (t == 255u) blocksum[b] = sc[255];
}

// ---------------- K2b: parallel scan, stage 2. Every block scans the 256
// blocksums (1KB, L2-hot) and adds its base to its cursor chunk.
__global__ void k_scan_b(const unsigned* __restrict__ blocksum,
                         unsigned* __restrict__ cursor) {
    __shared__ unsigned bs[256];
    unsigned t = threadIdx.x, b = blockIdx.x;
    bs[t] = blocksum[t];
    __syncthreads();
    for (unsigned off = 1u; off < 256u; off <<= 1) {
        unsigned v = (t >= off) ? bs[t - off] : 0u;
        __syncthreads();
        bs[t] += v;
        __syncthreads();
    }
    unsigned base_b = (b > 0u) ? bs[b - 1u] : 0u;
    if (base_b != 0u) cursor[b * 256u + t] += base_b;
}

// ---------------- K3: scatter keys (+slot payload) into descending-value
// order; rows >= np are exactly the all-zero output rows -> zero them here.
__global__ void k_scatter(const unsigned* __restrict__ counters,
                          const unsigned long long* __restrict__ keys,
                          unsigned* cursor, unsigned long long* sorted,
                          unsigned* sslot,
                          float4* __restrict__ out, float* __restrict__ valid) {
    unsigned np = counters[1]; if (np > PEAK_CAP) np = PEAK_CAP;
    unsigned t = blockIdx.x * 1024u + threadIdx.x;
    if (t < np) {
        unsigned long long key = keys[t];
        unsigned bits = (unsigned)(key >> 32);
        unsigned pos = atomicAdd(&cursor[(~bits) & 0xFFFFu], 1u);
        if (pos < PEAK_CAP) { sorted[pos] = key; sslot[pos] = t; }
    } else if (t < KPEAKS) {
        out[t] = make_float4(0.f, 0.f, 0.f, 0.f);
        valid[t] = 0.f;
    }
}

// ---------------- K4: tiefix + output fused. Each scatter position finds its
// tie-corrected row (equal-value runs ordered by ascending voxel idx, per
// lax.top_k) and writes the final output row directly. Bounded by np.
__global__ void k_finish(const unsigned* __restrict__ counters,
                         const unsigned long long* __restrict__ sorted,
                         const unsigned* __restrict__ sslot,
                         const float4* __restrict__ psums,
                         float4* __restrict__ out, float* __restrict__ valid) {
    unsigned np = counters[1]; if (np > PEAK_CAP) np = PEAK_CAP;
    unsigned t = blockIdx.x * 1024u + threadIdx.x;
    if (t >= np) return;
    unsigned long long key = sorted[t];
    unsigned bits = (unsigned)(key >> 32);
    unsigned s = t;
    while (s > 0 && (unsigned)(sorted[s - 1] >> 32) == bits) s--;
    unsigned myidx = (unsigned)key;
    unsigned rank = 0, e = s;
    while (e < np) {
        unsigned long long k2 = sorted[e];
        if ((unsigned)(k2 >> 32) != bits) break;
        if ((unsigned)k2 < myidx) rank++;
        e++;
    }
    unsigned row = s + rank;
    if (row >= KPEAKS) return;
    unsigned idx = myidx;
    int z = idx >> 18, y = (idx >> 9) & 511, x = idx & 511;
    float4 ps = psums[sslot[t]];
    float val = __uint_as_float(bits);
    float xloc = ps.y / ps.x, yloc = ps.z / ps.x, zloc = ps.w / ps.x;
    float xr = ((float)x + xloc - (float)(WW - 1) * 0.5f) * 0.1f;
    float yr = ((float)y + yloc - (float)(HH - 1) * 0.5f) * 0.1f;
    float zr = ((float)z + zloc + 0.5f) * 0.02f - 2.0f;
    out[row] = make_float4(xr, yr, zr, val);
    valid[row] = 1.f;
}

extern "C" void kernel_launch(void* const* d_in, const int* in_sizes, int n_in,
                              void* d_out, int out_size, void* d_ws, size_t ws_size,
                              hipStream_t stream) {
    const float* vol = (const float*)d_in[0];
    // d_in[1] = max_peaks scalar (device); fixed at 131072 for this problem.

    char* w = (char*)d_ws;
    unsigned* counters = (unsigned*)w;                                   // 1 KB
    unsigned* hist     = (unsigned*)(w + 1024);                          // 256 KB
    unsigned* cursor   = (unsigned*)(w + 1024 + NBINS * 4);              // 256 KB
    char* w2 = w + 1024 + 2 * NBINS * 4;
    unsigned long long* keys   = (unsigned long long*)w2;                // 2 MB
    unsigned long long* sorted = keys + PEAK_CAP;                        // 2 MB
    unsigned* sslot = (unsigned*)(sorted + PEAK_CAP);                    // 1 MB
    float4*   psums = (float4*)(sslot + PEAK_CAP);                       // 4 MB
    // total ~9.5 MB of ws

    // blocksum scratch for the 2-stage scan: reuse sslot's first 1KB (sslot
    // is first written by k_scatter, which runs after k_scan_b consumed it).
    unsigned* blocksum = sslot;

    float* out_rows = (float*)d_out;                 // (131072, 4)
    float* valid = out_rows + (size_t)KPEAKS * 4;    // (131072,)

    k_init<<<NBINS / 1024, 1024, 0, stream>>>(counters, hist);
    k_find<<<NVOX / 8192, 512, 0, stream>>>((const float4*)vol, vol, counters, hist, keys, psums);
    k_scan_a<<<256, 256, 0, stream>>>(hist, cursor, blocksum);
    k_scan_b<<<256, 256, 0, stream>>>(blocksum, cursor);
    k_scatter<<<PEAK_CAP / 1024, 1024, 0, stream>>>(counters, keys, cursor, sorted, sslot,
                                                    (float4*)out_rows, valid);
    k_finish<<<PEAK_CAP / 1024, 1024, 0, stream>>>(counters, sorted, sslot, psums,
                                                   (float4*)out_rows, valid);
}